// Round 4
// baseline (429.072 us; speedup 1.0000x reference)
//
#include <hip/hip_runtime.h>
#include <math.h>

#define HDIM 128

typedef unsigned int uint;
typedef unsigned short ushort;
typedef __attribute__((ext_vector_type(8))) short short8;
typedef __attribute__((ext_vector_type(4))) float f32x4;

// bf16 helpers (bit-level; bf16->fp32 exact, fp32->bf16 RNE)
__device__ __forceinline__ float bflo(uint u){ return __uint_as_float(u<<16); }
__device__ __forceinline__ float bfhi(uint u){ return __uint_as_float(u&0xffff0000u); }
__device__ __forceinline__ ushort f2bf(float f){
  uint x = __float_as_uint(f);
  return (ushort)((x + 0x7fffu + ((x>>16)&1u)) >> 16);
}
__device__ __forceinline__ uint pack2bf(float a, float b){
  return (uint)f2bf(a) | ((uint)f2bf(b)<<16);
}

// ---------- CSR build ----------
__global__ void k_zero(int* cnt, int n){
  int i = blockIdx.x*256 + threadIdx.x;
  if (i<n) cnt[i]=0;
}

// XCD-partitioned count: partition p=blockIdx&7 owns dst range [lo,hi);
// its cnt slice stays in that XCD's L2 -> local atomics, no line bouncing.
__global__ __launch_bounds__(256) void k_count(const int* __restrict__ dst, int* __restrict__ cnt,
                                               int e, int n){
  int p = blockIdx.x & 7;
  int R = (n + 7) >> 3;
  int lo = p*R, hi = min(n, lo+R);
  int nb = gridDim.x >> 3;
  int bi = blockIdx.x >> 3;
  int stride = nb*256;
  for (int i = bi*256 + threadIdx.x; i < e; i += stride){
    int d = dst[i];
    if (d >= lo && d < hi) atomicAdd(&cnt[d], 1);
  }
}

// scan1 also produces dis = rsqrt(deg+1)
__global__ void k_scan1(const int* __restrict__ cnt, int* __restrict__ off, int* __restrict__ bsum,
                        float* __restrict__ dis, int n){
  __shared__ int tmp[256];
  int t = threadIdx.x; int i = blockIdx.x*256 + t;
  int v = (i<n) ? cnt[i] : 0;
  if (i<n) dis[i] = rsqrtf((float)(v+1));
  tmp[t] = v; __syncthreads();
  for (int d=1; d<256; d<<=1){
    int a = (t>=d) ? tmp[t-d] : 0;
    __syncthreads(); tmp[t] += a; __syncthreads();
  }
  if (i<n) off[i] = tmp[t] - v;
  if (t==255) bsum[blockIdx.x] = tmp[255];
}

__global__ void k_scan2(const int* __restrict__ bsum, int* __restrict__ bpre, int nb){
  __shared__ int tmp[512];
  int t = threadIdx.x;
  int v = (t<nb) ? bsum[t] : 0;
  tmp[t] = v; __syncthreads();
  for (int d=1; d<512; d<<=1){
    int a = (t>=d) ? tmp[t-d] : 0;
    __syncthreads(); tmp[t] += a; __syncthreads();
  }
  if (t<nb) bpre[t] = tmp[t] - v;
}

__global__ void k_scan3(int* __restrict__ off, int* __restrict__ cur, const int* __restrict__ bpre, int n){
  int i = blockIdx.x*256 + threadIdx.x;
  if (i<n){ int o = off[i] + bpre[blockIdx.x]; off[i]=o; cur[i]=o; }
}

// XCD-partitioned scatter: partition owns a 1.6MB slice of cw -> writes merge
// into full lines inside one XCD's L2 instead of 64B-per-8B-record HBM evicts.
__global__ __launch_bounds__(256) void k_scatter(const int* __restrict__ src, const int* __restrict__ dst,
                          const float* __restrict__ dis, int* __restrict__ cur,
                          int2* __restrict__ cw, int e, int n){
  int p = blockIdx.x & 7;
  int R = (n + 7) >> 3;
  int lo = p*R, hi = min(n, lo+R);
  int nb = gridDim.x >> 3;
  int bi = blockIdx.x >> 3;
  int stride = nb*256;
  for (int i = bi*256 + threadIdx.x; i < e; i += stride){
    int d = dst[i];
    if (d >= lo && d < hi){
      int s = src[i];
      int pos = atomicAdd(&cur[d], 1);
      int2 v; v.x = s; v.y = __float_as_int(dis[s]*dis[d]);
      cw[pos] = v;
    }
  }
}

// ---------- W transpose + bf16: Wt[out][in] ----------
__global__ void k_wt(const float* __restrict__ W, ushort* __restrict__ Wt){
  int idx = blockIdx.x*256 + threadIdx.x;   // 16384 total
  int no = idx>>7, k = idx&127;
  Wt[idx] = f2bf(W[k*HDIM + no]);
}

// ---------- scalar aggregation: s = A_norm * x ----------
__global__ void k_sagg(const float* __restrict__ x, const int* __restrict__ off, const int* __restrict__ cnt,
                       const int2* __restrict__ cw, const float* __restrict__ dis,
                       float* __restrict__ s, int n){
  int i = blockIdx.x*256 + threadIdx.x;
  if (i>=n) return;
  int b = off[i], e = b + cnt[i];
  float di = dis[i];
  float acc = di*di*x[i];
  for (int k=b;k<e;k++){
    int2 v = cw[k];
    acc = fmaf(__int_as_float(v.y), x[v.x], acc);
  }
  s[i] = acc;
}

// h0[i][c] = relu(s[i]*W0[c] + b0[c]) -> bf16 table
__global__ void k_h0(const float* __restrict__ s, const float* __restrict__ W0, const float* __restrict__ b0,
                     uint* __restrict__ h, int n){
  int idx = blockIdx.x*256 + threadIdx.x;
  int i = idx>>5, c4 = idx&31;
  if (i>=n) return;
  float sv = s[i];
  float4 w = ((const float4*)W0)[c4];
  float4 b = ((const float4*)b0)[c4];
  float o0 = fmaxf(fmaf(sv,w.x,b.x),0.f);
  float o1 = fmaxf(fmaf(sv,w.y,b.y),0.f);
  float o2 = fmaxf(fmaf(sv,w.z,b.z),0.f);
  float o3 = fmaxf(fmaf(sv,w.w,b.w),0.f);
  uint2 o; o.x = pack2bf(o0,o1); o.y = pack2bf(o2,o3);
  ((uint2*)(h + (size_t)i*64))[c4] = o;
}

// ---------- wide aggregation: g(bf16) = A_norm * h(bf16) ; one wave per node ----------
// unroll-by-8: 8 independent gathers in flight per wave
__global__ __launch_bounds__(256) void k_wagg(const uint* __restrict__ h, const int* __restrict__ off,
                       const int* __restrict__ cnt, const int2* __restrict__ cw,
                       const float* __restrict__ dis, uint* __restrict__ g, int n){
  int wave = threadIdx.x>>6, lane = threadIdx.x&63;
  int i = blockIdx.x*4 + wave;
  if (i>=n) return;
  int b = off[i], e = b + cnt[i];
  float di = dis[i];
  float w2 = di*di;
  uint su = h[(size_t)i*64 + lane];
  float2 acc; acc.x = w2*bflo(su); acc.y = w2*bfhi(su);
  int k = b;
  for (; k+8<=e; k+=8){
    int2 v[8]; uint u[8];
    #pragma unroll
    for (int j=0;j<8;j++) v[j] = cw[k+j];
    #pragma unroll
    for (int j=0;j<8;j++) u[j] = h[(size_t)v[j].x*64 + lane];
    #pragma unroll
    for (int j=0;j<8;j++){
      float w = __int_as_float(v[j].y);
      acc.x = fmaf(w, bflo(u[j]), acc.x); acc.y = fmaf(w, bfhi(u[j]), acc.y);
    }
  }
  for (; k<e; ++k){
    int2 v = cw[k];
    uint u = h[(size_t)v.x*64 + lane];
    float w = __int_as_float(v.y);
    acc.x = fmaf(w, bflo(u), acc.x); acc.y = fmaf(w, bfhi(u), acc.y);
  }
  g[(size_t)i*64 + lane] = pack2bf(acc.x, acc.y);
}

// ---------- dense via MFMA: h' = relu(g @ W + b), bf16 in/out ----------
__global__ __launch_bounds__(256) void k_mm(const uint* __restrict__ g, const ushort* __restrict__ Wt,
                     const float* __restrict__ b, ushort* __restrict__ h, int n){
  __shared__ uint4 Ws4[2048];   // Wt[128][128] bf16, swizzled, 32KB
  __shared__ uint4 As4[1024];   // g[64][128] bf16, swizzled, 16KB
  int t = threadIdx.x;
  int n0 = blockIdx.x*64;

  const uint4* Wg = (const uint4*)Wt;
  #pragma unroll
  for (int i=0;i<8;i++){
    int c = t + i*256;
    int row = c>>4, slot = c&15;
    Ws4[row*16 + (slot^(row&7))] = Wg[c];
  }
  const uint4* Gg = (const uint4*)g;
  #pragma unroll
  for (int i=0;i<4;i++){
    int c = t + i*256;
    int row = c>>4, slot = c&15;
    uint4 v = make_uint4(0,0,0,0);
    if (n0 + row < n) v = Gg[(size_t)(n0+row)*16 + slot];
    As4[row*16 + (slot^(row&7))] = v;
  }
  __syncthreads();

  int w = t>>6, l = t&63;
  int lr = l&15, lg = l>>4;
  f32x4 acc[8];
  #pragma unroll
  for (int j=0;j<8;j++) acc[j] = (f32x4){0.f,0.f,0.f,0.f};

  float bv[8];
  #pragma unroll
  for (int j=0;j<8;j++) bv[j] = b[16*j + lr];

  #pragma unroll
  for (int s=0;s<4;s++){
    short8 a = *(const short8*)&As4[(16*w + lr)*16 + ((4*s + lg)^(lr&7))];
    #pragma unroll
    for (int j=0;j<8;j++){
      short8 bb = *(const short8*)&Ws4[(16*j + lr)*16 + ((4*s + lg)^(lr&7))];
      acc[j] = __builtin_amdgcn_mfma_f32_16x16x32_bf16(a, bb, acc[j], 0, 0, 0);
    }
  }

  #pragma unroll
  for (int j=0;j<8;j++){
    int col = 16*j + lr;
    #pragma unroll
    for (int q=0;q<4;q++){
      int node = n0 + 16*w + lg*4 + q;
      if (node < n){
        float v = fmaxf(acc[j][q] + bv[j], 0.f);
        h[(size_t)node*HDIM + col] = f2bf(v);
      }
    }
  }
}

// ---------- z[i] = h2(bf16)[i] . Wo ; one wave per node, shuffle reduce ----------
__global__ __launch_bounds__(256) void k_z(const uint* __restrict__ h, const float* __restrict__ Wo,
                    float* __restrict__ z, int n){
  int wave = threadIdx.x>>6, lane = threadIdx.x&63;
  int i = blockIdx.x*4 + wave;
  if (i>=n) return;
  uint u = h[(size_t)i*64 + lane];
  float2 wv = ((const float2*)Wo)[lane];
  float v = bflo(u)*wv.x + bfhi(u)*wv.y;
  #pragma unroll
  for (int o=32;o>0;o>>=1) v += __shfl_xor(v,o);
  if (lane==0) z[i]=v;
}

// ---------- y[i] = sigmoid(A_norm z + bo) ----------
__global__ void k_final(const float* __restrict__ z, const int* __restrict__ off, const int* __restrict__ cnt,
                        const int2* __restrict__ cw, const float* __restrict__ dis,
                        const float* __restrict__ bo, float* __restrict__ y, int n){
  int i = blockIdx.x*256 + threadIdx.x;
  if (i>=n) return;
  int b = off[i], e = b + cnt[i];
  float di = dis[i];
  float acc = di*di*z[i];
  for (int k=b;k<e;k++){
    int2 v = cw[k];
    acc = fmaf(__int_as_float(v.y), z[v.x], acc);
  }
  acc += bo[0];
  y[i] = 1.f/(1.f + expf(-acc));
}

extern "C" void kernel_launch(void* const* d_in, const int* in_sizes, int n_in,
                              void* d_out, int out_size, void* d_ws, size_t ws_size,
                              hipStream_t stream){
  const float* x  = (const float*)d_in[0];
  const int*   ei = (const int*)d_in[1];
  const float* W0 = (const float*)d_in[2];
  const float* b0 = (const float*)d_in[3];
  const float* W1 = (const float*)d_in[4];
  const float* b1 = (const float*)d_in[5];
  const float* W2 = (const float*)d_in[6];
  const float* b2 = (const float*)d_in[7];
  const float* Wo = (const float*)d_in[8];
  const float* bo = (const float*)d_in[9];
  int n = in_sizes[0];
  int e = in_sizes[1]/2;
  const int* src = ei;
  const int* dst = ei + e;
  float* y = (float*)d_out;

  char* p = (char*)d_ws;
  auto alloc = [&](size_t bytes)->void*{ void* r=p; p += (bytes+255)&~(size_t)255; return r; };
  int*    cnt  = (int*)   alloc((size_t)n*4);
  int*    off  = (int*)   alloc((size_t)n*4);
  int*    cur  = (int*)   alloc((size_t)n*4);
  int*    bsum = (int*)   alloc(512*4);
  int*    bpre = (int*)   alloc(512*4);
  float*  dis  = (float*) alloc((size_t)n*4);
  float*  sb   = (float*) alloc((size_t)n*4);
  float*  zb   = (float*) alloc((size_t)n*4);
  ushort* Wt1  = (ushort*)alloc((size_t)HDIM*HDIM*2);
  ushort* Wt2  = (ushort*)alloc((size_t)HDIM*HDIM*2);
  int2*   cw   = (int2*)  alloc((size_t)e*8);
  uint*   hb0  = (uint*)  alloc((size_t)n*64*4);   // bf16 tables, n x 128 ch
  uint*   hb1  = (uint*)  alloc((size_t)n*64*4);
  uint*   gbuf = (uint*)  alloc((size_t)n*64*4);   // bf16 aggregated features

  int nb = (n+255)/256;
  int mb = (n+63)/64;

  k_zero   <<<nb,256,0,stream>>>(cnt,n);
  k_count  <<<512,256,0,stream>>>(dst,cnt,e,n);
  k_scan1  <<<nb,256,0,stream>>>(cnt,off,bsum,dis,n);
  k_scan2  <<<1,512,0,stream>>>(bsum,bpre,nb);
  k_scan3  <<<nb,256,0,stream>>>(off,cur,bpre,n);
  k_scatter<<<512,256,0,stream>>>(src,dst,dis,cur,cw,e,n);
  k_wt     <<<64,256,0,stream>>>(W1,Wt1);
  k_wt     <<<64,256,0,stream>>>(W2,Wt2);

  k_sagg <<<nb,256,0,stream>>>(x,off,cnt,cw,dis,sb,n);
  k_h0   <<<(n*32+255)/256,256,0,stream>>>(sb,W0,b0,hb0,n);

  k_wagg <<<(n+3)/4,256,0,stream>>>(hb0,off,cnt,cw,dis,gbuf,n);
  k_mm   <<<mb,256,0,stream>>>(gbuf,Wt1,b1,(ushort*)hb1,n);

  k_wagg <<<(n+3)/4,256,0,stream>>>(hb1,off,cnt,cw,dis,gbuf,n);
  k_mm   <<<mb,256,0,stream>>>(gbuf,Wt2,b2,(ushort*)hb0,n);

  k_z    <<<(n+3)/4,256,0,stream>>>(hb0,Wo,zb,n);
  k_final<<<nb,256,0,stream>>>(zb,off,cnt,cw,dis,bo,y,n);
}